// Round 3
// baseline (3554.811 us; speedup 1.0000x reference)
//
#include <hip/hip_runtime.h>

#define SEQ 2048
#define BATCH 512
#define HDIM 128

__device__ __forceinline__ float fast_tanh(float x) {
    // tanh(x) = 1 - 2/(exp(2x)+1); exact saturation at +/-inf.
    float e = __expf(2.0f * x);
    return fmaf(-2.0f, __builtin_amdgcn_rcpf(e + 1.0f), 1.0f);
}

// DPP move with compile-time control; old=0 so unselected lanes contribute 0.
template<int CTRL>
__device__ __forceinline__ float dpp_mov(float x) {
    return __int_as_float(__builtin_amdgcn_update_dpp(
        0, __float_as_int(x), CTRL, 0xf, 0xf, false));
}

__global__ __launch_bounds__(64, 1)
void odenet_scan_kernel(const float* __restrict__ x,
                        const float* __restrict__ W1,
                        const float* __restrict__ b1,
                        const float* __restrict__ W2,
                        const float* __restrict__ b2,
                        const float* __restrict__ W3,
                        const float* __restrict__ b3,
                        float* __restrict__ out)
{
    const int l = threadIdx.x;      // 0..63 — ONE wave per chain, no barriers
    const int b = blockIdx.x;       // chain (batch element)
    const int c0 = 2 * l;           // this lane's output column pair: c0, c0+1

    __shared__ float h1s[HDIM];

    // Full W2 columns c0 and c0+1 pinned in the unified VGPR/AGPR file:
    // 256 regs of weights, reused 2048x. Loads are float2 -> fully coalesced.
    float w2a[HDIM], w2b[HDIM];
    #pragma unroll
    for (int k = 0; k < HDIM; ++k) {
        float2 w = *reinterpret_cast<const float2*>(&W2[k * HDIM + c0]);
        w2a[k] = w.x;
        w2b[k] = w.y;
    }

    const float2 w1x = *reinterpret_cast<const float2*>(&W1[c0]);        // W1[0][c0..c0+1]
    const float2 w1s = *reinterpret_cast<const float2*>(&W1[HDIM + c0]); // W1[1][c0..c0+1]
    const float2 b1v = *reinterpret_cast<const float2*>(&b1[c0]);
    const float2 b2v = *reinterpret_cast<const float2*>(&b2[c0]);
    const float w3v0 = W3[2 * c0 + 1];      // only column 1 of W3 survives
    const float w3v1 = W3[2 * c0 + 3];
    const float b31  = b3[1];

    float s = 0.0f;
    float xn = x[b];                        // x layout (S,B,1)

    for (int n = 0; n < SEQ; ++n) {
        // ---- layer 1: this lane's two h columns.
        float pre0 = fmaf(w1x.x, xn, fmaf(w1s.x, s, b1v.x));
        float pre1 = fmaf(w1x.y, xn, fmaf(w1s.y, s, b1v.y));
        float2 h;
        h.x = fast_tanh(pre0);
        h.y = fast_tanh(pre1);
        *reinterpret_cast<float2*>(&h1s[c0]) = h;   // ds_write_b64
        // Single wave: LDS pipe is in-order per wave; only a compiler fence needed.
        __builtin_amdgcn_wave_barrier();

        // prefetch next x (wave-uniform -> scalar path)
        float xnext = (n + 1 < SEQ) ? x[(n + 1) * BATCH + b] : 0.0f;

        // ---- layer 2: full-K matvec for cols c0,c0+1. Broadcast b128 reads.
        float pa = 0.0f, pb = 0.0f;
        const float4* h4 = reinterpret_cast<const float4*>(h1s);
        #pragma unroll
        for (int k = 0; k < 32; ++k) {
            float4 hv = h4[k];
            pa = fmaf(w2a[4 * k + 0], hv.x, pa);
            pb = fmaf(w2b[4 * k + 0], hv.x, pb);
            pa = fmaf(w2a[4 * k + 1], hv.y, pa);
            pb = fmaf(w2b[4 * k + 1], hv.y, pb);
            pa = fmaf(w2a[4 * k + 2], hv.z, pa);
            pb = fmaf(w2b[4 * k + 2], hv.z, pb);
            pa = fmaf(w2a[4 * k + 3], hv.w, pa);
            pb = fmaf(w2b[4 * k + 3], hv.w, pb);
        }
        __builtin_amdgcn_wave_barrier();   // keep these reads before next iter's write

        // ---- layer 2 tanh + W3 col-1 dot + wave sum (DPP) — all in-wave.
        float h20 = fast_tanh(pa + b2v.x);
        float h21 = fast_tanh(pb + b2v.y);
        float z = fmaf(h20, w3v0, h21 * w3v1);

        z += dpp_mov<0x111>(z);   // row_shr:1
        z += dpp_mov<0x112>(z);   // row_shr:2
        z += dpp_mov<0x114>(z);   // row_shr:4
        z += dpp_mov<0x118>(z);   // row_shr:8
        z += dpp_mov<0x142>(z);   // row_bcast:15
        z += dpp_mov<0x143>(z);   // row_bcast:31
        float y = __int_as_float(__builtin_amdgcn_readlane(__float_as_int(z), 63));

        s = s + y + b31;
        if (l == 0) out[n * BATCH + b] = s;
        xn = xnext;
    }
}

extern "C" void kernel_launch(void* const* d_in, const int* in_sizes, int n_in,
                              void* d_out, int out_size, void* d_ws, size_t ws_size,
                              hipStream_t stream) {
    const float* x  = (const float*)d_in[0];
    const float* W1 = (const float*)d_in[1];
    const float* b1 = (const float*)d_in[2];
    const float* W2 = (const float*)d_in[3];
    const float* b2 = (const float*)d_in[4];
    const float* W3 = (const float*)d_in[5];
    const float* b3 = (const float*)d_in[6];
    float* out = (float*)d_out;

    dim3 grid(BATCH);
    dim3 block(64);
    odenet_scan_kernel<<<grid, block, 0, stream>>>(x, W1, b1, W2, b2, W3, b3, out);
}

// Round 4
// 2589.466 us; speedup vs baseline: 1.3728x; 1.3728x over previous
//
#include <hip/hip_runtime.h>

#define SEQ 2048
#define BATCH 512
#define HDIM 128

__device__ __forceinline__ float fast_tanh(float x) {
    // tanh(x) = 1 - 2/(exp(2x)+1); exact saturation at +/-inf.
    float e = __expf(2.0f * x);
    return fmaf(-2.0f, __builtin_amdgcn_rcpf(e + 1.0f), 1.0f);
}

// DPP move with compile-time control; old=0 so unselected lanes contribute 0.
template<int CTRL>
__device__ __forceinline__ float dpp_mov(float x) {
    return __int_as_float(__builtin_amdgcn_update_dpp(
        0, __float_as_int(x), CTRL, 0xf, 0xf, false));
}

__global__ __launch_bounds__(128, 1)
void odenet_scan_kernel(const float* __restrict__ x,
                        const float* __restrict__ W1,
                        const float* __restrict__ b1,
                        const float* __restrict__ W2,
                        const float* __restrict__ b2,
                        const float* __restrict__ W3,
                        const float* __restrict__ b3,
                        float* __restrict__ out)
{
    const int t = threadIdx.x;
    const int l = t & 63;            // lane
    const int q = t >> 6;            // wave: owns output cols [64q, 64q+64)
    const int c = q * 64 + l;        // this lane's output column (full K)
    const int b0 = 2 * blockIdx.x;   // two chains per block: b0, b0+1

    // Wave-private h1 buffers (each wave computes full h1 redundantly for
    // both chains -> matvec needs NO cross-wave barrier).
    __shared__ float h1buf[2][2][HDIM];   // [wave][chain][k]
    __shared__ float ybuf[2][2][2];       // [parity][wave][chain] partial y

    // Full W2 column c pinned in regs (128 floats/lane; R2-verified budget).
    float w2r[HDIM];
    #pragma unroll
    for (int k = 0; k < HDIM; ++k)
        w2r[k] = W2[k * HDIM + c];

    // h1 params for the two columns (2l, 2l+1) this lane produces.
    const float2 w1x = *reinterpret_cast<const float2*>(&W1[2 * l]);
    const float2 w1s = *reinterpret_cast<const float2*>(&W1[HDIM + 2 * l]);
    const float2 b1v = *reinterpret_cast<const float2*>(&b1[2 * l]);

    const float b2v = b2[c];
    const float w3v = W3[2 * c + 1];      // only column 1 of W3 survives
    const float b31 = b3[1];

    float s0 = 0.0f, s1 = 0.0f;
    float2 xn = *reinterpret_cast<const float2*>(&x[b0]);   // x layout (S,B,1)

    for (int n = 0; n < SEQ; ++n) {
        const int par = n & 1;

        // ---- layer 1 (both chains, cols 2l, 2l+1) -> wave-private LDS.
        float2 hA, hB;
        hA.x = fast_tanh(fmaf(w1x.x, xn.x, fmaf(w1s.x, s0, b1v.x)));
        hA.y = fast_tanh(fmaf(w1x.y, xn.x, fmaf(w1s.y, s0, b1v.y)));
        hB.x = fast_tanh(fmaf(w1x.x, xn.y, fmaf(w1s.x, s1, b1v.x)));
        hB.y = fast_tanh(fmaf(w1x.y, xn.y, fmaf(w1s.y, s1, b1v.y)));
        *reinterpret_cast<float2*>(&h1buf[q][0][2 * l]) = hA;
        *reinterpret_cast<float2*>(&h1buf[q][1][2 * l]) = hB;
        __builtin_amdgcn_wave_barrier();  // order: in-wave LDS write -> read

        // prefetch next x pair (uniform address, overlaps matvec)
        float2 xnext = make_float2(0.0f, 0.0f);
        if (n + 1 < SEQ)
            xnext = *reinterpret_cast<const float2*>(&x[(n + 1) * BATCH + b0]);

        // ---- layer 2: full-K matvec for col c, both chains interleaved.
        float pa = 0.0f, pb = 0.0f;
        const float4* hA4 = reinterpret_cast<const float4*>(h1buf[q][0]);
        const float4* hB4 = reinterpret_cast<const float4*>(h1buf[q][1]);
        #pragma unroll
        for (int k = 0; k < 32; ++k) {
            float4 va = hA4[k];
            float4 vb = hB4[k];
            pa = fmaf(w2r[4 * k + 0], va.x, pa);
            pb = fmaf(w2r[4 * k + 0], vb.x, pb);
            pa = fmaf(w2r[4 * k + 1], va.y, pa);
            pb = fmaf(w2r[4 * k + 1], vb.y, pb);
            pa = fmaf(w2r[4 * k + 2], va.z, pa);
            pb = fmaf(w2r[4 * k + 2], vb.z, pb);
            pa = fmaf(w2r[4 * k + 3], va.w, pa);
            pb = fmaf(w2r[4 * k + 3], vb.w, pb);
        }
        __builtin_amdgcn_wave_barrier();  // keep reads before next iter's write

        // ---- layer 2 tanh + W3 col-1 contribution, both chains.
        float za = fast_tanh(pa + b2v) * w3v;
        float zb = fast_tanh(pb + b2v) * w3v;

        // wave64 sum via DPP (two chains interleave -> latency hidden).
        za += dpp_mov<0x111>(za);  zb += dpp_mov<0x111>(zb);
        za += dpp_mov<0x112>(za);  zb += dpp_mov<0x112>(zb);
        za += dpp_mov<0x114>(za);  zb += dpp_mov<0x114>(zb);
        za += dpp_mov<0x118>(za);  zb += dpp_mov<0x118>(zb);
        za += dpp_mov<0x142>(za);  zb += dpp_mov<0x142>(zb);
        za += dpp_mov<0x143>(za);  zb += dpp_mov<0x143>(zb);

        if (l == 63)
            *reinterpret_cast<float2*>(&ybuf[par][q][0]) = make_float2(za, zb);
        __syncthreads();   // the ONLY block barrier: 4-float scalar exchange

        const float4 yv = *reinterpret_cast<const float4*>(&ybuf[par][0][0]);
        s0 = s0 + (yv.x + yv.z) + b31;    // y = wave0 + wave1 partials
        s1 = s1 + (yv.y + yv.w) + b31;

        if (t == 0)
            *reinterpret_cast<float2*>(&out[n * BATCH + b0]) = make_float2(s0, s1);
        xn = xnext;
    }
}

extern "C" void kernel_launch(void* const* d_in, const int* in_sizes, int n_in,
                              void* d_out, int out_size, void* d_ws, size_t ws_size,
                              hipStream_t stream) {
    const float* x  = (const float*)d_in[0];
    const float* W1 = (const float*)d_in[1];
    const float* b1 = (const float*)d_in[2];
    const float* W2 = (const float*)d_in[3];
    const float* b2 = (const float*)d_in[4];
    const float* W3 = (const float*)d_in[5];
    const float* b3 = (const float*)d_in[6];
    float* out = (float*)d_out;

    dim3 grid(BATCH / 2);   // 2 chains per block
    dim3 block(128);        // 2 waves
    odenet_scan_kernel<<<grid, block, 0, stream>>>(x, W1, b1, W2, b2, W3, b3, out);
}

// Round 6
// 1559.945 us; speedup vs baseline: 2.2788x; 1.6600x over previous
//
#include <hip/hip_runtime.h>

#define SEQ 2048
#define BATCH 512
#define HDIM 128

__device__ __forceinline__ float fast_tanh(float x) {
    // tanh(x) = 1 - 2/(exp(2x)+1); exact saturation at +/-inf.
    float e = __expf(2.0f * x);
    return fmaf(-2.0f, __builtin_amdgcn_rcpf(e + 1.0f), 1.0f);
}

// x + dpp_mov<CTRL>(x); old=0 so unselected/invalid lanes contribute 0.
template<int CTRL>
__device__ __forceinline__ float dpp_add(float x) {
    return x + __int_as_float(__builtin_amdgcn_update_dpp(
        0, __float_as_int(x), CTRL, 0xf, 0xf, false));
}

__global__ __launch_bounds__(128, 1)
void odenet_scan_kernel(const float* __restrict__ x,
                        const float* __restrict__ W1,
                        const float* __restrict__ b1,
                        const float* __restrict__ W2,
                        const float* __restrict__ b2,
                        const float* __restrict__ W3,
                        const float* __restrict__ b3,
                        float* __restrict__ out)
{
    const int t  = threadIdx.x;
    const int l  = t & 63;          // lane
    const int q  = t >> 6;          // wave: owns output cols [64q, 64q+64)
    const int j  = l >> 2;          // quad within wave
    const int kq = l & 3;           // K-quarter: k in [32kq, 32kq+32)
    const int c0 = 64 * q + 4 * j;  // first of this lane's 4 output columns
    const int b  = blockIdx.x;      // one chain per block

    __shared__ float xbuf[SEQ];          // 8 KB: all x for this chain
    __shared__ float h1buf[2][4 * 36];   // per-wave padded h1 (group g at 36g)
    __shared__ float ybuf[2][2];         // [parity][wave] scalar y-partials

    // ---- one-time: preload x (kills ALL per-step global loads).
    {
        float v[16];
        #pragma unroll
        for (int i = 0; i < 16; ++i)
            v[i] = x[(i * 128 + t) * BATCH + b];
        #pragma unroll
        for (int i = 0; i < 16; ++i)
            xbuf[i * 128 + t] = v[i];
    }

    // ---- one-time: pin W2 sub-block in regs: 4 cols x 32 k = 128 floats.
    float wc0[32], wc1[32], wc2[32], wc3[32];
    #pragma unroll
    for (int kk = 0; kk < 32; ++kk) {
        float4 wv = *reinterpret_cast<const float4*>(&W2[(32 * kq + kk) * HDIM + c0]);
        wc0[kk] = wv.x; wc1[kk] = wv.y; wc2[kk] = wv.z; wc3[kk] = wv.w;
    }

    // h1 params for the two h-columns (2l, 2l+1) this lane produces (per wave).
    const float2 w1x = *reinterpret_cast<const float2*>(&W1[2 * l]);
    const float2 w1s = *reinterpret_cast<const float2*>(&W1[HDIM + 2 * l]);
    const float2 b1v = *reinterpret_cast<const float2*>(&b1[2 * l]);
    // layer-2/3 params for cols c0..c0+3; w3 pre-scaled by 0.25 to cancel the
    // exact x4 duplication of z within each quad after the DPP combine.
    const float4 b2v = *reinterpret_cast<const float4*>(&b2[c0]);
    const float w3s0 = W3[(c0 + 0) * 2 + 1] * 0.25f;
    const float w3s1 = W3[(c0 + 1) * 2 + 1] * 0.25f;
    const float w3s2 = W3[(c0 + 2) * 2 + 1] * 0.25f;
    const float w3s3 = W3[(c0 + 3) * 2 + 1] * 0.25f;
    const float b31  = b3[1];

    // h write offset: position p=2l -> group p>>5 (=l>>4), slot p&31.
    const int hoff = 36 * (l >> 4) + ((2 * l) & 31);
    const float4* h4 = reinterpret_cast<const float4*>(&h1buf[q][kq * 36]);

    __syncthreads();   // preload visible to both waves

    float s = 0.0f;
    float s_hold = 0.0f;
    float xn = xbuf[0];

    for (int n = 0; n < SEQ; ++n) {
        const int par = n & 1;

        // ---- layer 1: two h columns -> wave-private LDS (redundant per wave).
        float ha = fast_tanh(fmaf(w1x.x, xn, fmaf(w1s.x, s, b1v.x)));
        float hb = fast_tanh(fmaf(w1x.y, xn, fmaf(w1s.y, s, b1v.y)));
        *reinterpret_cast<float2*>(&h1buf[q][hoff]) = make_float2(ha, hb);
        __builtin_amdgcn_wave_barrier();   // order in-wave LDS write -> reads

        // next step's x from LDS (off critical path; &-wrap avoids OOB at tail)
        float xnext = xbuf[(n + 1) & (SEQ - 1)];

        // ---- layer 2: 4 cols x 32 K per lane; 8 broadcast b128 reads, 128 FMA.
        float p0 = 0.0f, p1 = 0.0f, p2 = 0.0f, p3 = 0.0f;
        #pragma unroll
        for (int i = 0; i < 8; ++i) {
            float4 hv = h4[i];
            p0 = fmaf(wc0[4 * i + 0], hv.x, p0);
            p1 = fmaf(wc1[4 * i + 0], hv.x, p1);
            p2 = fmaf(wc2[4 * i + 0], hv.x, p2);
            p3 = fmaf(wc3[4 * i + 0], hv.x, p3);
            p0 = fmaf(wc0[4 * i + 1], hv.y, p0);
            p1 = fmaf(wc1[4 * i + 1], hv.y, p1);
            p2 = fmaf(wc2[4 * i + 1], hv.y, p2);
            p3 = fmaf(wc3[4 * i + 1], hv.y, p3);
            p0 = fmaf(wc0[4 * i + 2], hv.z, p0);
            p1 = fmaf(wc1[4 * i + 2], hv.z, p1);
            p2 = fmaf(wc2[4 * i + 2], hv.z, p2);
            p3 = fmaf(wc3[4 * i + 2], hv.z, p3);
            p0 = fmaf(wc0[4 * i + 3], hv.w, p0);
            p1 = fmaf(wc1[4 * i + 3], hv.w, p1);
            p2 = fmaf(wc2[4 * i + 3], hv.w, p2);
            p3 = fmaf(wc3[4 * i + 3], hv.w, p3);
        }
        __builtin_amdgcn_wave_barrier();   // keep reads before next iter's write

        // ---- combine K-quarters within each quad: 2 DPP adds per col.
        p0 = dpp_add<0xB1>(p0); p0 = dpp_add<0x4E>(p0);   // quad_perm(1,0,3,2),(2,3,0,1)
        p1 = dpp_add<0xB1>(p1); p1 = dpp_add<0x4E>(p1);
        p2 = dpp_add<0xB1>(p2); p2 = dpp_add<0x4E>(p2);
        p3 = dpp_add<0xB1>(p3); p3 = dpp_add<0x4E>(p3);

        // ---- layer 2 tanh + W3 col-1 dot (z duplicated x4 in quad; prescaled).
        float z;
        z = fast_tanh(p0 + b2v.x) * w3s0;
        z = fmaf(fast_tanh(p1 + b2v.y), w3s1, z);
        z = fmaf(fast_tanh(p2 + b2v.z), w3s2, z);
        z = fmaf(fast_tanh(p3 + b2v.w), w3s3, z);

        // ---- wave64 sum: row_shr/bcast cascade; full sum lands in lane 63.
        z = dpp_add<0x111>(z);   // row_shr:1
        z = dpp_add<0x112>(z);   // row_shr:2
        z = dpp_add<0x114>(z);   // row_shr:4
        z = dpp_add<0x118>(z);   // row_shr:8
        z = dpp_add<0x142>(z);   // row_bcast:15
        z = dpp_add<0x143>(z);   // row_bcast:31

        if (l == 63) ybuf[par][q] = z;     // this wave's y-partial
        __syncthreads();   // ONLY block barrier; vmcnt already 0 -> cheap drain

        const float2 yv = *reinterpret_cast<const float2*>(&ybuf[par][0]);
        s = s + (yv.x + yv.y) + b31;

        // ---- out batching (wave 0): one scatter store per 64 steps.
        if (q == 0) {
            if (l == (n & 63)) s_hold = s;
            if ((n & 63) == 63) out[(n - 63 + l) * BATCH + b] = s_hold;
        }
        xn = xnext;
    }
}

extern "C" void kernel_launch(void* const* d_in, const int* in_sizes, int n_in,
                              void* d_out, int out_size, void* d_ws, size_t ws_size,
                              hipStream_t stream) {
    const float* x  = (const float*)d_in[0];
    const float* W1 = (const float*)d_in[1];
    const float* b1 = (const float*)d_in[2];
    const float* W2 = (const float*)d_in[3];
    const float* b2 = (const float*)d_in[4];
    const float* W3 = (const float*)d_in[5];
    const float* b3 = (const float*)d_in[6];
    float* out = (float*)d_out;

    dim3 grid(BATCH);    // one chain per block
    dim3 block(128);     // 2 waves
    odenet_scan_kernel<<<grid, block, 0, stream>>>(x, W1, b1, W2, b2, W3, b3, out);
}

// Round 7
// 1063.274 us; speedup vs baseline: 3.3433x; 1.4671x over previous
//
#include <hip/hip_runtime.h>

#define SEQ 2048
#define BATCH 512
#define HDIM 128

typedef float f32x2 __attribute__((ext_vector_type(2)));

__device__ __forceinline__ float fast_tanh(float x) {
    // tanh(x) = 1 - 2/(exp(2x)+1); exact saturation at +/-inf.
    float e = __expf(2.0f * x);
    return fmaf(-2.0f, __builtin_amdgcn_rcpf(e + 1.0f), 1.0f);
}

// x + dpp_mov<CTRL>(x); old=0 so unselected/invalid lanes contribute 0.
template<int CTRL>
__device__ __forceinline__ float dpp_add(float x) {
    return x + __int_as_float(__builtin_amdgcn_update_dpp(
        0, __float_as_int(x), CTRL, 0xf, 0xf, false));
}

__global__ __launch_bounds__(256, 2)
void odenet_scan_kernel(const float* __restrict__ x,
                        const float* __restrict__ W1,
                        const float* __restrict__ b1,
                        const float* __restrict__ W2,
                        const float* __restrict__ b2,
                        const float* __restrict__ W3,
                        const float* __restrict__ b3,
                        float* __restrict__ out)
{
    const int t  = threadIdx.x;
    const int l  = t & 63;            // lane
    const int w  = t >> 6;            // wave 0..3: owns output cols [32w, 32w+32)
    const int pr = l >> 2;            // pair index: cols 32w+2pr, 32w+2pr+1
    const int kq = l & 3;             // K-quarter: k in [32kq, 32kq+32)
    const int c0 = 32 * w + 2 * pr;   // first of this lane's 2 output columns
    const int b  = blockIdx.x;        // one chain per block

    __shared__ float xbuf[SEQ];           // 8 KB: all x for this chain
    __shared__ float h1buf[4][4 * 36];    // per-wave padded h1 (group g at 36g)
    __shared__ float ybuf[2][4];          // [parity][wave] scalar y-partials

    // ---- one-time: preload x (kills ALL per-step global loads).
    {
        float v[8];
        #pragma unroll
        for (int i = 0; i < 8; ++i)
            v[i] = x[(i * 256 + t) * BATCH + b];
        #pragma unroll
        for (int i = 0; i < 8; ++i)
            xbuf[i * 256 + t] = v[i];
    }

    // ---- one-time: pin W2 sub-block: 2 cols x 32 k, K-packed into f32x2.
    f32x2 wA[16], wB[16];
    #pragma unroll
    for (int i = 0; i < 16; ++i) {
        const int k0 = 32 * kq + 2 * i;
        wA[i] = f32x2{W2[k0 * HDIM + c0],     W2[(k0 + 1) * HDIM + c0]};
        wB[i] = f32x2{W2[k0 * HDIM + c0 + 1], W2[(k0 + 1) * HDIM + c0 + 1]};
    }

    // h1 params for the two h-columns (2l, 2l+1) this lane produces (per wave).
    const float2 w1x = *reinterpret_cast<const float2*>(&W1[2 * l]);
    const float2 w1s = *reinterpret_cast<const float2*>(&W1[HDIM + 2 * l]);
    const float2 b1v = *reinterpret_cast<const float2*>(&b1[2 * l]);
    // layer-2/3 params; w3 pre-scaled by 0.25 (each col duplicated x4 in quad).
    const float2 b2v = *reinterpret_cast<const float2*>(&b2[c0]);
    const float w3s0 = W3[(c0 + 0) * 2 + 1] * 0.25f;
    const float w3s1 = W3[(c0 + 1) * 2 + 1] * 0.25f;
    const float b31  = b3[1];

    // h write offset: position p=2l -> group p>>5 (=l>>4), slot p&31.
    const int hoff = 36 * (l >> 4) + ((2 * l) & 31);
    const float4* h4 = reinterpret_cast<const float4*>(&h1buf[w][36 * kq]);

    __syncthreads();   // preload visible to all waves

    float s = 0.0f;
    float s_hold = 0.0f;
    float xn = xbuf[0];

    for (int n = 0; n < SEQ; ++n) {
        const int par = n & 1;

        // ---- layer 1: two h columns -> wave-private LDS (redundant per wave).
        float ha = fast_tanh(fmaf(w1x.x, xn, fmaf(w1s.x, s, b1v.x)));
        float hb = fast_tanh(fmaf(w1x.y, xn, fmaf(w1s.y, s, b1v.y)));
        *reinterpret_cast<float2*>(&h1buf[w][hoff]) = make_float2(ha, hb);
        __builtin_amdgcn_wave_barrier();   // order in-wave LDS write -> reads

        // next step's x from LDS (broadcast, off critical path)
        float xnext = xbuf[(n + 1) & (SEQ - 1)];

        // ---- layer 2: 2 cols x 32 K per lane; 8 b128 reads, 32 v_pk_fma_f32.
        f32x2 accA = {0.0f, 0.0f}, accB = {0.0f, 0.0f};
        #pragma unroll
        for (int i = 0; i < 8; ++i) {
            float4 hv = h4[i];
            f32x2 hp0 = {hv.x, hv.y};
            f32x2 hp1 = {hv.z, hv.w};
            accA = __builtin_elementwise_fma(wA[2 * i],     hp0, accA);
            accB = __builtin_elementwise_fma(wB[2 * i],     hp0, accB);
            accA = __builtin_elementwise_fma(wA[2 * i + 1], hp1, accA);
            accB = __builtin_elementwise_fma(wB[2 * i + 1], hp1, accB);
        }
        __builtin_amdgcn_wave_barrier();   // keep reads before next iter's write

        // ---- horizontal + K-quarter combine within quad (2 DPP adds per col).
        float p0 = accA.x + accA.y;
        float p1 = accB.x + accB.y;
        p0 = dpp_add<0xB1>(p0); p0 = dpp_add<0x4E>(p0);   // quad_perm(1,0,3,2),(2,3,0,1)
        p1 = dpp_add<0xB1>(p1); p1 = dpp_add<0x4E>(p1);

        // ---- layer 2 tanh + W3 col-1 dot (cols duplicated x4; w3 prescaled).
        float z = fast_tanh(p0 + b2v.x) * w3s0;
        z = fmaf(fast_tanh(p1 + b2v.y), w3s1, z);

        // ---- wave64 sum: row_shr/bcast cascade; full sum lands in lane 63.
        z = dpp_add<0x111>(z);   // row_shr:1
        z = dpp_add<0x112>(z);   // row_shr:2
        z = dpp_add<0x114>(z);   // row_shr:4
        z = dpp_add<0x118>(z);   // row_shr:8
        z = dpp_add<0x142>(z);   // row_bcast:15
        z = dpp_add<0x143>(z);   // row_bcast:31

        if (l == 63) ybuf[par][w] = z;     // this wave's 32-col partial
        __syncthreads();   // ONLY block barrier; vmcnt already 0 -> cheap drain

        const float4 yv = *reinterpret_cast<const float4*>(&ybuf[par][0]);
        s = s + ((yv.x + yv.y) + (yv.z + yv.w)) + b31;

        // ---- out batching (wave 0): one scatter store per 64 steps.
        if (w == 0) {
            if (l == (n & 63)) s_hold = s;
            if ((n & 63) == 63) out[(n - 63 + l) * BATCH + b] = s_hold;
        }
        xn = xnext;
    }
}

extern "C" void kernel_launch(void* const* d_in, const int* in_sizes, int n_in,
                              void* d_out, int out_size, void* d_ws, size_t ws_size,
                              hipStream_t stream) {
    const float* x  = (const float*)d_in[0];
    const float* W1 = (const float*)d_in[1];
    const float* b1 = (const float*)d_in[2];
    const float* W2 = (const float*)d_in[3];
    const float* b2 = (const float*)d_in[4];
    const float* W3 = (const float*)d_in[5];
    const float* b3 = (const float*)d_in[6];
    float* out = (float*)d_out;

    dim3 grid(BATCH);    // one chain per block
    dim3 block(256);     // 4 waves
    odenet_scan_kernel<<<grid, block, 0, stream>>>(x, W1, b1, W2, b2, W3, b3, out);
}